// Round 1
// baseline (167.303 us; speedup 1.0000x reference)
//
#include <hip/hip_runtime.h>
#include <hip/hip_fp16.h>

#define NG 32
#define NC 33
#define BATCH 4096

// level1: [33][33][32][16][32] f32, 17,842,176 elems
// level0: [33][33][64][16]     f32,  1,115,136 elems
static constexpr size_t T1H_BYTES = 17842176ull * 2;     // fp16 transposed level1
static constexpr size_t T0F_BYTES = 1115136ull * 4;      // f32 transposed level0

__device__ __forceinline__ void interp1(float v, const float* sb, const float* sil,
                                        int& i, float& d) {
    float e = expf(-fabsf(v));
    float s = (v > 0.f) ? (1.f - 0.5f * e) : (0.5f * e);
    s *= (float)NG;
    int ii = (int)s;                       // trunc (s >= 0)
    ii = ii < 0 ? 0 : (ii > NG - 1 ? NG - 1 : ii);
    d = (v - sb[ii]) * sil[ii];
    i = ii;
}

// ---------------------------------------------------------------------------
// Kernel 1: transpose tables.
//   level1[a][b'][o][x][z] (f32) -> T1[(x*32+z)*1089 + a*33+b'][o] (fp16)
//   level0[a][b'][h][p]    (f32) -> T0[(p*1089 + a*33+b')*64 + h] (f32)
// one block per cell (a,b'); slabs are contiguous in the source.
// ---------------------------------------------------------------------------
__global__ __launch_bounds__(256) void k_transpose(
    const float* __restrict__ L1, const float* __restrict__ L0,
    __half* __restrict__ T1, float* __restrict__ T0)
{
    __shared__ __half hbuf[32 * 514];   // [o][xz] padded (+2 halves) for bank-free reads
    __shared__ float  fbuf[64 * 17];    // [h][p] padded
    const int cell = blockIdx.x;        // a*33 + b'

    const size_t base1 = (size_t)cell * 16384;   // 32*16*32
    for (int t = threadIdx.x; t < 16384; t += 256) {
        float v = L1[base1 + t];
        int o = t >> 9, r = t & 511;             // t = o*512 + (x*32+z)
        hbuf[o * 514 + r] = __float2half(v);
    }
    const size_t base0 = (size_t)cell * 1024;    // 64*16
    for (int t = threadIdx.x; t < 1024; t += 256) {
        int h = t >> 4, p = t & 15;              // t = h*16 + p
        fbuf[h * 17 + p] = L0[base0 + t];
    }
    __syncthreads();
    for (int t = threadIdx.x; t < 16384; t += 256) {
        int xz = t >> 5, o = t & 31;
        T1[((size_t)xz * 1089 + cell) * 32 + o] = hbuf[o * 514 + xz];
    }
    for (int t = threadIdx.x; t < 1024; t += 256) {
        int p = t >> 6, h = t & 63;
        T0[((size_t)p * 1089 + cell) * 64 + h] = fbuf[h * 17 + p];
    }
}

// ---------------------------------------------------------------------------
// Kernel 2: interp params + z0 + second-level interp params.
// block = 4 batch elems x 64 h-lanes.
// ---------------------------------------------------------------------------
__global__ __launch_bounds__(256) void k_prep(
    const float* __restrict__ X, const float* __restrict__ T0,
    const float* __restrict__ borders, const float* __restrict__ invlen,
    int* __restrict__ i1x, float* __restrict__ wx0, float* __restrict__ wx1,
    int* __restrict__ j1z, float* __restrict__ wz0, float* __restrict__ wz1)
{
    __shared__ float sb[33], sil[32];
    __shared__ int   scell[16][4];
    __shared__ float sw[4][16][4];   // w00,w01,w10,w11 per (p, b-local)
    __shared__ float sz0[4][64];

    const int tid = threadIdx.x;
    if (tid < 33) sb[tid] = borders[tid];
    if (tid >= 64 && tid < 96) sil[tid - 64] = invlen[tid - 64];
    const int h = tid & 63, bl = tid >> 6;
    const int b = blockIdx.x * 4 + bl;
    __syncthreads();

    if (h < 16) {
        const int p = h;
        float x1 = X[(2 * p) * BATCH + b];
        float x2 = X[(2 * p + 1) * BATCH + b];
        int i1, i2; float d1, d2;
        interp1(x1, sb, sil, i1, d1);
        interp1(x2, sb, sil, i2, d2);
        float w00 = (1.f - d1) * (1.f - d2);
        float w01 = (1.f - d1) * d2;
        float w10 = d1 * (1.f - d2);
        float w11 = d1 * d2;
        scell[p][bl] = i1 * 33 + i2;
        sw[0][p][bl] = w00; sw[1][p][bl] = w01; sw[2][p][bl] = w10; sw[3][p][bl] = w11;
        i1x[p * BATCH + b] = i1;
        wx0[p * BATCH + b] = w00;   // pairs with corner i1
        wx1[p * BATCH + b] = w10;   // pairs with corner i1+1
    }
    __syncthreads();

    // z0[h] = sum_p bilinear lookups from T0 (lanes h coalesced, 256B/load)
    float acc = 0.f;
#pragma unroll 4
    for (int p = 0; p < 16; ++p) {
        int cell = scell[p][bl];
        unsigned basep = ((unsigned)p * 1089u + (unsigned)cell) * 64u + (unsigned)h;
        float t00 = T0[basep];
        float t01 = T0[basep + 64];
        float t10 = T0[basep + 33 * 64];
        float t11 = T0[basep + 34 * 64];
        acc += sw[0][p][bl] * t00 + sw[1][p][bl] * t01 + sw[2][p][bl] * t10 + sw[3][p][bl] * t11;
    }
    sz0[bl][h] = acc;
    __syncthreads();

    if (tid < 128) {
        const int z = tid & 31, bl2 = tid >> 5;
        const int b2 = blockIdx.x * 4 + bl2;
        float z1 = sz0[bl2][2 * z];
        float z2 = sz0[bl2][2 * z + 1];
        int j1, j2u; float dz1, dz2;
        interp1(z1, sb, sil, j1, dz1);
        interp1(z2, sb, sil, j2u, dz2);
        (void)j2u;
        j1z[z * BATCH + b2] = j1;
        wz0[z * BATCH + b2] = (1.f - dz1) * (1.f - dz2);  // corner j1
        wz1[z * BATCH + b2] = dz1 * (1.f - dz2);          // corner j1+1
    }
}

// ---------------------------------------------------------------------------
// Kernel 3: main gather-accumulate.
// thread = (b = wave, oh in 0..3 (8 o's each), zs in 0..7 (4 z's), xs in 0..1 (8 x's))
// lane = xs<<5 | zs<<2 | oh  -> 4 oh lanes adjacent => 64B coalesced corner loads.
// ---------------------------------------------------------------------------
__device__ __forceinline__ void accum8(float acc[8], uint4 u, float c) {
    union { unsigned u32; __half2 h2; } cv;
    cv.u32 = u.x; { float2 f = __half22float2(cv.h2); acc[0] = fmaf(c, f.x, acc[0]); acc[1] = fmaf(c, f.y, acc[1]); }
    cv.u32 = u.y; { float2 f = __half22float2(cv.h2); acc[2] = fmaf(c, f.x, acc[2]); acc[3] = fmaf(c, f.y, acc[3]); }
    cv.u32 = u.z; { float2 f = __half22float2(cv.h2); acc[4] = fmaf(c, f.x, acc[4]); acc[5] = fmaf(c, f.y, acc[5]); }
    cv.u32 = u.w; { float2 f = __half22float2(cv.h2); acc[6] = fmaf(c, f.x, acc[6]); acc[7] = fmaf(c, f.y, acc[7]); }
}

__global__ __launch_bounds__(256, 4) void k_main(
    const __half* __restrict__ T1,
    const int* __restrict__ i1x, const float* __restrict__ wx0, const float* __restrict__ wx1,
    const int* __restrict__ j1z, const float* __restrict__ wz0, const float* __restrict__ wz1,
    float* __restrict__ out)
{
    __shared__ int   si1[16][4];
    __shared__ float sx0[16][4], sx1[16][4];
    __shared__ int   sj1[32][4];
    __shared__ float sz0w[32][4], sz1w[32][4];

    const int tid = threadIdx.x;
    const int b0 = blockIdx.x * 4;

    if (tid < 64) {
        int p = tid >> 2, bl = tid & 3;
        int idx = p * BATCH + b0 + bl;
        si1[p][bl] = i1x[idx]; sx0[p][bl] = wx0[idx]; sx1[p][bl] = wx1[idx];
    }
    if (tid < 128) {
        int z = tid >> 2, bl = tid & 3;
        int idx = z * BATCH + b0 + bl;
        sj1[z][bl] = j1z[idx]; sz0w[z][bl] = wz0[idx]; sz1w[z][bl] = wz1[idx];
    }
    __syncthreads();

    const int lane = tid & 63, wid = tid >> 6;
    const int oh = lane & 3;
    const int zs = (lane >> 2) & 7;
    const int xs = lane >> 5;
    const int bl = wid;
    const int b = b0 + bl;

    float acc[8];
#pragma unroll
    for (int k = 0; k < 8; ++k) acc[k] = 0.f;

#pragma unroll 2
    for (int xi = 0; xi < 8; ++xi) {
        const int x = xs * 8 + xi;
        const int i1 = si1[x][bl];
        const float X0 = sx0[x][bl], X1 = sx1[x][bl];
        const int xbase = x * 32;
#pragma unroll
        for (int zi = 0; zi < 4; ++zi) {
            const int z = zs * 4 + zi;
            const int j1 = sj1[z][bl];
            const float Z0 = sz0w[z][bl], Z1 = sz1w[z][bl];
            const unsigned hb = (((unsigned)(xbase + z) * 1089u) + (unsigned)(i1 * 33 + j1)) * 32u
                                + (unsigned)(oh * 8);
            uint4 u00 = *reinterpret_cast<const uint4*>(T1 + hb);
            uint4 u01 = *reinterpret_cast<const uint4*>(T1 + hb + 32);        // (i1, j1+1)
            uint4 u10 = *reinterpret_cast<const uint4*>(T1 + hb + 33 * 32);   // (i1+1, j1)
            uint4 u11 = *reinterpret_cast<const uint4*>(T1 + hb + 34 * 32);   // (i1+1, j1+1)
            const float c00 = X0 * Z0, c01 = X0 * Z1, c10 = X1 * Z0, c11 = X1 * Z1;
            accum8(acc, u00, c00);
            accum8(acc, u01, c01);
            accum8(acc, u10, c10);
            accum8(acc, u11, c11);
        }
    }

    // reduce over zs (lane bits 2..4) and xs (lane bit 5)
#pragma unroll
    for (int m = 4; m <= 32; m <<= 1) {
#pragma unroll
        for (int k = 0; k < 8; ++k) acc[k] += __shfl_xor(acc[k], m, 64);
    }
    if (lane < 4) {
#pragma unroll
        for (int k = 0; k < 8; ++k) out[(oh * 8 + k) * BATCH + b] = acc[k];
    }
}

extern "C" void kernel_launch(void* const* d_in, const int* in_sizes, int n_in,
                              void* d_out, int out_size, void* d_ws, size_t ws_size,
                              hipStream_t stream) {
    const float* X       = (const float*)d_in[0];
    const float* L0      = (const float*)d_in[1];
    const float* L1      = (const float*)d_in[2];
    const float* borders = (const float*)d_in[3];
    const float* invlen  = (const float*)d_in[4];
    float* out = (float*)d_out;

    char* ws = (char*)d_ws;
    __half* T1h = (__half*)ws;                               // 35,684,352 B
    float*  T0f = (float*)(ws + T1H_BYTES);                  //  4,460,544 B
    char* p = ws + T1H_BYTES + T0F_BYTES;
    int*   i1x = (int*)p;            p += 16 * BATCH * 4;
    float* wx0 = (float*)p;          p += 16 * BATCH * 4;
    float* wx1 = (float*)p;          p += 16 * BATCH * 4;
    int*   j1z = (int*)p;            p += 32 * BATCH * 4;
    float* wz0 = (float*)p;          p += 32 * BATCH * 4;
    float* wz1 = (float*)p;          p += 32 * BATCH * 4;

    hipLaunchKernelGGL(k_transpose, dim3(1089), dim3(256), 0, stream, L1, L0, T1h, T0f);
    hipLaunchKernelGGL(k_prep, dim3(BATCH / 4), dim3(256), 0, stream,
                       X, T0f, borders, invlen, i1x, wx0, wx1, j1z, wz0, wz1);
    hipLaunchKernelGGL(k_main, dim3(BATCH / 4), dim3(256), 0, stream,
                       T1h, i1x, wx0, wx1, j1z, wz0, wz1, out);
}

// Round 5
// 149.569 us; speedup vs baseline: 1.1186x; 1.1186x over previous
//
#include <hip/hip_runtime.h>
#include <hip/hip_fp16.h>

#define NG 32
#define BATCH 4096

// level1: [33][33][32][16][32] f32 -> T1[(x*32+z)*1089 + a*33+b'][o] fp16
// level0: [33][33][64][16]     f32 -> T0[(p*1089 + a*33+b')*64 + h]  f32
static constexpr size_t T1H_BYTES = 17842176ull * 2;
static constexpr size_t T0F_BYTES = 1115136ull * 4;

__device__ __forceinline__ void interp1(float v, const float* sb, const float* sil,
                                        int& i, float& d) {
    float e = expf(-fabsf(v));
    float s = (v > 0.f) ? (1.f - 0.5f * e) : (0.5f * e);
    s *= (float)NG;
    int ii = (int)s;                       // trunc (s >= 0)
    ii = ii < 0 ? 0 : (ii > NG - 1 ? NG - 1 : ii);
    d = (v - sb[ii]) * sil[ii];
    i = ii;
}

// ---------------------------------------------------------------------------
// Kernel 1: transpose tables (one block per cell a*33+b').
// ---------------------------------------------------------------------------
__global__ __launch_bounds__(256) void k_transpose(
    const float* __restrict__ L1, const float* __restrict__ L0,
    __half* __restrict__ T1, float* __restrict__ T0)
{
    __shared__ __half hbuf[32 * 516];   // [o][xz] pad 516: 8B-aligned rows, <=2-way banks
    __shared__ float  fbuf[64 * 17];    // [h][p] pad
    const int cell = blockIdx.x;
    const int tid = threadIdx.x;

    // stage level1 slab: 16384 floats as 4096 float4, convert to fp16
    const float4* L1v = reinterpret_cast<const float4*>(L1 + (size_t)cell * 16384);
#pragma unroll
    for (int k = 0; k < 16; ++k) {
        int v = tid + k * 256;                 // float4 index
        int idx = v * 4;
        int o = idx >> 9, r = idx & 511;       // same o for all 4 floats
        float4 f = L1v[v];
        *reinterpret_cast<__half2*>(&hbuf[o * 516 + r])     = __float22half2_rn(make_float2(f.x, f.y));
        *reinterpret_cast<__half2*>(&hbuf[o * 516 + r + 2]) = __float22half2_rn(make_float2(f.z, f.w));
    }
    // stage level0 slab: 1024 floats
    const float* L0s = L0 + (size_t)cell * 1024;
#pragma unroll
    for (int k = 0; k < 4; ++k) {
        int t = tid + k * 256;
        int h = t >> 4, p = t & 15;
        fbuf[h * 17 + p] = L0s[t];
    }
    __syncthreads();

    // write T1: 2048 uint4 (8 halves each), contiguous per xz row
#pragma unroll
    for (int k = 0; k < 8; ++k) {
        int t = tid + k * 256;
        int xz = t >> 2, o0 = (t & 3) * 8;
        __half tmp[8];
#pragma unroll
        for (int j = 0; j < 8; ++j) tmp[j] = hbuf[(o0 + j) * 516 + xz];
        *reinterpret_cast<uint4*>(&T1[((size_t)xz * 1089 + cell) * 32 + o0]) =
            *reinterpret_cast<const uint4*>(tmp);
    }
    // write T0: coalesced 4B/lane over h
#pragma unroll
    for (int k = 0; k < 4; ++k) {
        int t = tid + k * 256;
        int p = t >> 6, h = t & 63;
        T0[((size_t)p * 1089 + cell) * 64 + h] = fbuf[h * 17 + p];
    }
}

// ---------------------------------------------------------------------------
// Kernel 2: fused prep + main gather-accumulate. Block = 4 batch elems.
// Main-loop lane layout: lane = zs*8 + jc*4 + oh
//   oh (0..3): o-octet; jc (0..1): j-corner; zs (0..7): z-slice of 4
//   -> each load instr: 8 lanes cover 128B contiguous (2 j-corners x 32 o fp16)
// ---------------------------------------------------------------------------
__device__ __forceinline__ void accumh2(__half2 acc[4], uint4 u, __half2 c) {
    union { unsigned u32; __half2 h2; } cv;
    cv.u32 = u.x; acc[0] = __hfma2(c, cv.h2, acc[0]);
    cv.u32 = u.y; acc[1] = __hfma2(c, cv.h2, acc[1]);
    cv.u32 = u.z; acc[2] = __hfma2(c, cv.h2, acc[2]);
    cv.u32 = u.w; acc[3] = __hfma2(c, cv.h2, acc[3]);
}

__global__ __launch_bounds__(256, 4) void k_fused(
    const float* __restrict__ X, const float* __restrict__ T0,
    const __half* __restrict__ T1,
    const float* __restrict__ borders, const float* __restrict__ invlen,
    float* __restrict__ out)
{
    __shared__ float sb[33], sil[32];
    __shared__ int   scell[16][4];
    __shared__ float ssw[4][16][4];
    __shared__ float sz0[4][64];
    __shared__ int   si1[16][4];
    __shared__ float sX0[16][4], sX1[16][4];
    __shared__ int   sj1[32][4];
    __shared__ float sZ[2][32][4];

    const int tid = threadIdx.x;
    const int b0 = blockIdx.x * 4;

    if (tid < 33) sb[tid] = borders[tid];
    if (tid >= 64 && tid < 96) sil[tid - 64] = invlen[tid - 64];
    __syncthreads();

    // phase 0: first-level interp (16 p x 4 b)
    if (tid < 64) {
        const int p = tid & 15, bl = tid >> 4;
        const int b = b0 + bl;
        float x1 = X[(2 * p) * BATCH + b];
        float x2 = X[(2 * p + 1) * BATCH + b];
        int i1, i2; float d1, d2;
        interp1(x1, sb, sil, i1, d1);
        interp1(x2, sb, sil, i2, d2);
        float w00 = (1.f - d1) * (1.f - d2);
        float w01 = (1.f - d1) * d2;
        float w10 = d1 * (1.f - d2);
        float w11 = d1 * d2;
        scell[p][bl] = i1 * 33 + i2;
        ssw[0][p][bl] = w00; ssw[1][p][bl] = w01; ssw[2][p][bl] = w10; ssw[3][p][bl] = w11;
        si1[p][bl] = i1;
        sX0[p][bl] = w00;   // pairs corner i1
        sX1[p][bl] = w10;   // pairs corner i1+1
    }
    __syncthreads();

    // phase 1: z0[h] (64 h-lanes x 4 b, coalesced 256B loads from T0)
    {
        const int h = tid & 63, bl = tid >> 6;
        float acc = 0.f;
#pragma unroll 4
        for (int p = 0; p < 16; ++p) {
            int cell = scell[p][bl];
            unsigned basep = ((unsigned)p * 1089u + (unsigned)cell) * 64u + (unsigned)h;
            float t00 = T0[basep];
            float t01 = T0[basep + 64];
            float t10 = T0[basep + 33 * 64];
            float t11 = T0[basep + 34 * 64];
            acc += ssw[0][p][bl] * t00 + ssw[1][p][bl] * t01 + ssw[2][p][bl] * t10 + ssw[3][p][bl] * t11;
        }
        sz0[bl][h] = acc;
    }
    __syncthreads();

    // phase 2: second-level interp (32 z x 4 b)
    if (tid < 128) {
        const int z = tid & 31, bl = tid >> 5;
        float z1 = sz0[bl][2 * z];
        float z2 = sz0[bl][2 * z + 1];
        int j1, j2u; float dz1, dz2;
        interp1(z1, sb, sil, j1, dz1);
        interp1(z2, sb, sil, j2u, dz2);
        (void)j2u;
        sj1[z][bl] = j1;
        sZ[0][z][bl] = (1.f - dz1) * (1.f - dz2);  // corner j1
        sZ[1][z][bl] = dz1 * (1.f - dz2);          // corner j1+1
    }
    __syncthreads();

    // phase 3: main gather loop
    const int lane = tid & 63, bl = tid >> 6;
    const int b = b0 + bl;
    const int oh = lane & 3;
    const int jc = (lane >> 2) & 1;
    const int zs = lane >> 3;
    const unsigned loff = (unsigned)(jc * 32 + oh * 8);

    __half2 acc2[4];
#pragma unroll
    for (int k = 0; k < 4; ++k) acc2[k] = __half2half2(__float2half(0.f));

#pragma unroll 2
    for (int x = 0; x < 16; ++x) {
        const int cb = si1[x][bl] * 33;
        const float X0 = sX0[x][bl], X1 = sX1[x][bl];
        const unsigned xzb = (unsigned)(x * 32 + zs * 4) * 1089u;
#pragma unroll
        for (int zi = 0; zi < 4; ++zi) {
            const int z = zs * 4 + zi;
            const unsigned cell = (unsigned)(cb + sj1[z][bl]);
            const float Zc = sZ[jc][z][bl];
            const unsigned base = (xzb + (unsigned)zi * 1089u + cell) * 32u + loff;
            uint4 u0 = *reinterpret_cast<const uint4*>(T1 + base);            // (i1,   j1+jc)
            uint4 u1 = *reinterpret_cast<const uint4*>(T1 + base + 33 * 32);  // (i1+1, j1+jc)
            const float c0 = X0 * Zc, c1 = X1 * Zc;
            accumh2(acc2, u0, __float2half2_rn(c0));
            accumh2(acc2, u1, __float2half2_rn(c1));
        }
    }

    // unpack to fp32, butterfly-reduce over jc (mask 4) and zs (8,16,32)
    float accf[8];
#pragma unroll
    for (int k = 0; k < 4; ++k) {
        float2 f = __half22float2(acc2[k]);
        accf[2 * k] = f.x; accf[2 * k + 1] = f.y;
    }
#pragma unroll
    for (int m = 4; m <= 32; m <<= 1) {
#pragma unroll
        for (int k = 0; k < 8; ++k) accf[k] += __shfl_xor(accf[k], m, 64);
    }
    if (lane < 4) {
#pragma unroll
        for (int k = 0; k < 8; ++k) out[(oh * 8 + k) * BATCH + b] = accf[k];
    }
}

extern "C" void kernel_launch(void* const* d_in, const int* in_sizes, int n_in,
                              void* d_out, int out_size, void* d_ws, size_t ws_size,
                              hipStream_t stream) {
    const float* X       = (const float*)d_in[0];
    const float* L0      = (const float*)d_in[1];
    const float* L1      = (const float*)d_in[2];
    const float* borders = (const float*)d_in[3];
    const float* invlen  = (const float*)d_in[4];
    float* out = (float*)d_out;

    char* ws = (char*)d_ws;
    __half* T1h = (__half*)ws;
    float*  T0f = (float*)(ws + T1H_BYTES);

    hipLaunchKernelGGL(k_transpose, dim3(1089), dim3(256), 0, stream, L1, L0, T1h, T0f);
    hipLaunchKernelGGL(k_fused, dim3(BATCH / 4), dim3(256), 0, stream,
                       X, T0f, T1h, borders, invlen, out);
}